// Round 1
// baseline (216.149 us; speedup 1.0000x reference)
//
#include <hip/hip_runtime.h>
#include <stdint.h>

using u16 = unsigned short;
using u32 = unsigned int;
using f32x4 = __attribute__((ext_vector_type(4))) float;
using s16x8 = __attribute__((ext_vector_type(8))) short;

#define DEVINL __device__ __forceinline__

// problem constants
constexpr int B_ = 4, K_ = 4096, C_ = 384, HID_ = 1536, H_ = 32, W_ = 32, L_ = 8192;
constexpr int M_ = B_ * K_; // 16384 total tokens

DEVINL u16 f2bf(float f) {
    u32 u = __builtin_bit_cast(u32, f);
    u32 r = (u + 0x7FFFu + ((u >> 16) & 1u)) >> 16;
    return (u16)r;
}
DEVINL float bf2f(u16 h) {
    u32 u = ((u32)h) << 16;
    return __builtin_bit_cast(float, u);
}

// ---------------- prep: convert x_sparse fp32 -> bf16 ----------------
__global__ __launch_bounds__(256) void convert_x_kernel(const float* __restrict__ x,
                                                        u16* __restrict__ out) {
    const int i = blockIdx.x * 256 + threadIdx.x; // 786432 items, 8 elems each
    const float4* p = (const float4*)(x + (size_t)i * 8);
    float4 a = p[0], b = p[1];
    s16x8 o;
    o[0] = (short)f2bf(a.x); o[1] = (short)f2bf(a.y);
    o[2] = (short)f2bf(a.z); o[3] = (short)f2bf(a.w);
    o[4] = (short)f2bf(b.x); o[5] = (short)f2bf(b.y);
    o[6] = (short)f2bf(b.z); o[7] = (short)f2bf(b.w);
    *(s16x8*)(out + (size_t)i * 8) = o;
}

// ---------------- prep: weights + dw transpose + pos2k scatter ----------------
// virtual index space:
//   [0, 73728)        : w1 convert, 8 elems each  (1536*384 = 589824)
//   [73728, 147456)   : w2 convert, 8 elems each
//   [147456, 161280)  : dwT[j][h] = dw_w[h*9 + j]   (13824 scalars)
//   [161280, 177664)  : pos2k scatter (16384 tokens)
__global__ __launch_bounds__(256) void prep_small_kernel(
    const float* __restrict__ w1, const float* __restrict__ w2,
    const float* __restrict__ dww, const int* __restrict__ indices,
    u16* __restrict__ w1b, u16* __restrict__ w2b,
    float* __restrict__ dwT, int* __restrict__ pos2k) {
    const int i = blockIdx.x * 256 + threadIdx.x; // grid = 694 * 256 = 177664 exactly
    if (i < 147456) {
        const float* src = (i < 73728) ? (w1 + (size_t)i * 8) : (w2 + (size_t)(i - 73728) * 8);
        u16* dst = (i < 73728) ? (w1b + (size_t)i * 8) : (w2b + (size_t)(i - 73728) * 8);
        float4 a = ((const float4*)src)[0];
        float4 b = ((const float4*)src)[1];
        s16x8 o;
        o[0] = (short)f2bf(a.x); o[1] = (short)f2bf(a.y);
        o[2] = (short)f2bf(a.z); o[3] = (short)f2bf(a.w);
        o[4] = (short)f2bf(b.x); o[5] = (short)f2bf(b.y);
        o[6] = (short)f2bf(b.z); o[7] = (short)f2bf(b.w);
        *(s16x8*)dst = o;
    } else if (i < 161280) {
        int t = i - 147456;
        int j = t / 1536;
        int hh = t - j * 1536;
        dwT[j * 1536 + hh] = dww[hh * 9 + j];
    } else {
        int t = i - 161280;          // token id 0..16383
        int b = t >> 12;             // /K_
        pos2k[(b << 13) + indices[t]] = t & 4095;
    }
}

// ---------------- GEMM: C[M,N] = A[M,K] * Bt[N,K]^T + bias, m97 structure ----------------
template <bool OUT_BF16>
__global__ __launch_bounds__(256) void gemm_bt_kernel(
    const u16* __restrict__ A,   // [M,K] bf16 row-major
    const u16* __restrict__ Bt,  // [N,K] bf16 row-major
    const float* __restrict__ bias, // [N]
    void* __restrict__ Cv,       // [M,N] row-major (bf16 or f32)
    int Mdim, int Ndim, int Kdim) {
    constexpr int BK = 32;
    __shared__ u16 As[128 * BK];
    __shared__ u16 Bs[128 * BK];

    const int tid = threadIdx.x;
    const int wave = tid >> 6;
    const int lane = tid & 63;
    const int row0 = blockIdx.x * 128;
    const int col0 = blockIdx.y * 128;

    // staging: each wave stages chunks {2w, 2w+1} of A and of B (1 KB each)
    const int sr = lane >> 2;         // row within 16-row chunk
    const int sc = (lane & 3) * 8;    // k-offset (8 bf16 = 16 B)

    // compute geometry: wave (wr,wc) owns 64x64; 4x4 frags of 16x16
    const int wr = (wave >> 1) * 64;
    const int wc = (wave & 1) * 64;
    const int fq = lane >> 4;         // 0..3
    const int fr = lane & 15;         // 0..15

    f32x4 acc[4][4];
#pragma unroll
    for (int m = 0; m < 4; ++m)
#pragma unroll
        for (int n = 0; n < 4; ++n) acc[m][n] = f32x4{0.f, 0.f, 0.f, 0.f};

    const int ch0 = wave * 2;
    for (int k0 = 0; k0 < Kdim; k0 += BK) {
        __syncthreads(); // protect LDS from previous iteration's readers
#pragma unroll
        for (int cc = 0; cc < 2; ++cc) {
            const int ch = ch0 + cc;
            const int r = ch * 16 + sr;
            const u16* gA = A + (size_t)(row0 + r) * Kdim + k0 + sc;
            __builtin_amdgcn_global_load_lds(
                (const __attribute__((address_space(1))) void*)gA,
                (__attribute__((address_space(3))) void*)(As + ch * 512), 16, 0, 0);
            const u16* gB = Bt + (size_t)(col0 + r) * Kdim + k0 + sc;
            __builtin_amdgcn_global_load_lds(
                (const __attribute__((address_space(1))) void*)gB,
                (__attribute__((address_space(3))) void*)(Bs + ch * 512), 16, 0, 0);
        }
        __syncthreads(); // compiler emits vmcnt(0) drain before barrier

        s16x8 af[4], bf_[4];
#pragma unroll
        for (int m = 0; m < 4; ++m)
            af[m] = *(const s16x8*)(As + (wr + m * 16 + fr) * 32 + fq * 8);
#pragma unroll
        for (int n = 0; n < 4; ++n)
            bf_[n] = *(const s16x8*)(Bs + (wc + n * 16 + fr) * 32 + fq * 8);
#pragma unroll
        for (int m = 0; m < 4; ++m)
#pragma unroll
            for (int n = 0; n < 4; ++n)
                acc[m][n] = __builtin_amdgcn_mfma_f32_16x16x32_bf16(af[m], bf_[n], acc[m][n], 0, 0, 0);
    }

    // epilogue: C/D layout col = lane&15, row = (lane>>4)*4 + j  (m89-verified)
#pragma unroll
    for (int n = 0; n < 4; ++n) {
        const int col = col0 + wc + n * 16 + fr;
        const float bv = bias[col];
#pragma unroll
        for (int m = 0; m < 4; ++m) {
            const int rowb = row0 + wr + m * 16 + fq * 4;
#pragma unroll
            for (int j = 0; j < 4; ++j) {
                float v = acc[m][n][j] + bv;
                if constexpr (OUT_BF16)
                    ((u16*)Cv)[(size_t)(rowb + j) * Ndim + col] = f2bf(v);
                else
                    ((float*)Cv)[(size_t)(rowb + j) * Ndim + col] = v;
            }
        }
    }
}

// ---------------- depthwise 3x3 conv on active tokens + GELU ----------------
// one block per token, 192 threads, 8 channels/thread
__global__ __launch_bounds__(192) void conv_gelu_kernel(
    const u16* __restrict__ h,       // [M, HID] bf16 (compact, token-major)
    const int* __restrict__ indices, // [B,K]
    const int* __restrict__ pos2k,   // [B,L] (-1 if inactive)
    const float* __restrict__ dwT,   // [9, HID]
    const float* __restrict__ dwb,   // [HID]
    u16* __restrict__ g)             // [M, HID] bf16
{
    const int token = blockIdx.x;
    const int b = token >> 12;       // /K_
    const int c0 = threadIdx.x * 8;
    const int pos = indices[token];
    const int x = pos & 31;
    const int y = (pos >> 5) & 31;
    const int tb = pos & ~1023;      // t * H*W

    float acc[8];
    {
        float4 b0 = *(const float4*)(dwb + c0);
        float4 b1 = *(const float4*)(dwb + c0 + 4);
        acc[0] = b0.x; acc[1] = b0.y; acc[2] = b0.z; acc[3] = b0.w;
        acc[4] = b1.x; acc[5] = b1.y; acc[6] = b1.z; acc[7] = b1.w;
    }

#pragma unroll
    for (int dy = -1; dy <= 1; ++dy) {
        const int yy = y + dy;
        if (yy < 0 || yy >= 32) continue;
#pragma unroll
        for (int dx = -1; dx <= 1; ++dx) {
            const int xx = x + dx;
            if (xx < 0 || xx >= 32) continue;
            const int np = tb + (yy << 5) + xx;
            const int kp = pos2k[(b << 13) + np];
            if (kp < 0) continue;
            const int j = (dy + 1) * 3 + (dx + 1);
            const s16x8 hv = *(const s16x8*)(h + ((size_t)(b << 12) + kp) * 1536 + c0);
            const float* wp = dwT + j * 1536 + c0;
            const float4 w0 = *(const float4*)wp;
            const float4 w1v = *(const float4*)(wp + 4);
            acc[0] += bf2f((u16)hv[0]) * w0.x;
            acc[1] += bf2f((u16)hv[1]) * w0.y;
            acc[2] += bf2f((u16)hv[2]) * w0.z;
            acc[3] += bf2f((u16)hv[3]) * w0.w;
            acc[4] += bf2f((u16)hv[4]) * w1v.x;
            acc[5] += bf2f((u16)hv[5]) * w1v.y;
            acc[6] += bf2f((u16)hv[6]) * w1v.z;
            acc[7] += bf2f((u16)hv[7]) * w1v.w;
        }
    }

    s16x8 o;
#pragma unroll
    for (int q = 0; q < 8; ++q) {
        const float v = acc[q];
        const float gl = 0.5f * v * (1.0f + erff(v * 0.70710678118654752440f));
        o[q] = (short)f2bf(gl);
    }
    *(s16x8*)(g + (size_t)token * 1536 + c0) = o;
}

extern "C" void kernel_launch(void* const* d_in, const int* in_sizes, int n_in,
                              void* d_out, int out_size, void* d_ws, size_t ws_size,
                              hipStream_t stream) {
    (void)in_sizes; (void)n_in; (void)out_size; (void)ws_size;
    const float* x   = (const float*)d_in[0];
    const int* indices = (const int*)d_in[1];
    // d_in[2..5] are scalars B,L,H,W (known constants)
    const float* w1  = (const float*)d_in[6];
    const float* b1  = (const float*)d_in[7];
    const float* dww = (const float*)d_in[8];
    const float* dwb = (const float*)d_in[9];
    const float* w2  = (const float*)d_in[10];
    const float* b2  = (const float*)d_in[11];

    char* ws = (char*)d_ws;
    size_t off = 0;
    auto alloc = [&](size_t bytes) -> void* {
        void* p = ws + off;
        off += (bytes + 255) & ~(size_t)255;
        return p;
    };
    u16*   Abf   = (u16*)alloc((size_t)M_ * C_ * 2);      // 12.6 MB
    u16*   W1b   = (u16*)alloc((size_t)HID_ * C_ * 2);    // 1.2 MB
    u16*   W2b   = (u16*)alloc((size_t)C_ * HID_ * 2);    // 1.2 MB
    float* dwT   = (float*)alloc((size_t)9 * HID_ * 4);   // 55 KB
    int*   pos2k = (int*)alloc((size_t)B_ * L_ * 4);      // 128 KB
    u16*   hbuf  = (u16*)alloc((size_t)M_ * HID_ * 2);    // 50.3 MB
    u16*   gbuf  = (u16*)alloc((size_t)M_ * HID_ * 2);    // 50.3 MB

    hipMemsetAsync(pos2k, 0xFF, (size_t)B_ * L_ * 4, stream);
    convert_x_kernel<<<3072, 256, 0, stream>>>(x, Abf);
    prep_small_kernel<<<694, 256, 0, stream>>>(w1, w2, dww, indices, W1b, W2b, dwT, pos2k);

    dim3 g1(M_ / 128, HID_ / 128); // 128 x 12
    gemm_bt_kernel<true><<<g1, 256, 0, stream>>>(Abf, W1b, b1, hbuf, M_, HID_, C_);

    conv_gelu_kernel<<<M_, 192, 0, stream>>>(hbuf, indices, pos2k, dwT, dwb, gbuf);

    dim3 g2(M_ / 128, C_ / 128);   // 128 x 3
    gemm_bt_kernel<false><<<g2, 256, 0, stream>>>(gbuf, W2b, b2, (float*)d_out, M_, C_, HID_);
}